// Round 9
// baseline (79.592 us; speedup 1.0000x reference)
//
#include <hip/hip_runtime.h>
#include <math.h>

#define B_    8
#define N_    1024
#define FIN   512
#define FOUT  256
#define ALPHA 0.2f
#define EPSV  1e-5f

typedef __attribute__((ext_vector_type(8))) short bf16x8;
typedef __attribute__((ext_vector_type(4))) float f32x4;

__device__ __forceinline__ short f2bf(float x) {          // RNE
    unsigned u = __builtin_bit_cast(unsigned, x);
    u = (u + 0x7FFFu + ((u >> 16) & 1u)) >> 16;
    return (short)u;
}
__device__ __forceinline__ short f2bf_fast(float x) {     // round-half-up (P path)
    unsigned u = __builtin_bit_cast(unsigned, x);
    return (short)((u + 0x8000u) >> 16);
}
__device__ __forceinline__ float bf2f(short s) {
    return __builtin_bit_cast(float, ((unsigned)(unsigned short)s) << 16);
}
__device__ __forceinline__ float gelu_exact(float x) {
    return 0.5f * x * (1.0f + erff(x * 0.70710678118654752f));
}

// Bpack fragment-linear chunks (1 KB = 64 lanes x 16B):
//   Bpack[b][n16][kt][l][u8] : lane l=(lq*16+lr) holds Wh[kt*32+lq*8+u][n16*16+lr]

// ---------------------------------------------------------------------------
// k_prep: W (512x256 fp32 row-major) -> WT (256x512 bf16, [col][k]).
// ---------------------------------------------------------------------------
__global__ __launch_bounds__(256) void k_prep(const float* __restrict__ W,
                                              short* __restrict__ WT) {
    int id  = blockIdx.x * 256 + threadIdx.x;
    int col = id >> 7;
    int k4  = (id & 127) * 4;
    short4 v;
    v.x = f2bf(W[(k4 + 0) * FOUT + col]);
    v.y = f2bf(W[(k4 + 1) * FOUT + col]);
    v.z = f2bf(W[(k4 + 2) * FOUT + col]);
    v.w = f2bf(W[(k4 + 3) * FOUT + col]);
    *(short4*)(WT + (long)col * FIN + k4) = v;
}

// ---------------------------------------------------------------------------
// k_wh: Wh = h @ W via bf16 MFMA; writes Bpack (fragment-linear) + F1/F2.
// Block = 256 thr / 4 waves; 16 node-rows; grid = 512.
// ---------------------------------------------------------------------------
__global__ __launch_bounds__(256) void k_wh(const float* __restrict__ h,
                                            const short* __restrict__ WT,
                                            const float* __restrict__ a,
                                            short* __restrict__ Bpack,
                                            float* __restrict__ F1,
                                            float* __restrict__ F2) {
    const int tid = threadIdx.x;
    const int w   = tid >> 6, l = tid & 63;
    const int lr  = l & 15, lq = l >> 4;
    const long row0 = (long)blockIdx.x * 16;
    const int colbase = w * 64;

    __shared__ float r1[4][16], r2[4][16];

    f32x4 acc[4] = {};
    const float* hrow = h + (row0 + lr) * FIN + lq * 8;

    #pragma unroll
    for (int k0 = 0; k0 < FIN; k0 += 32) {
        float4 v0 = *(const float4*)(hrow + k0);
        float4 v1 = *(const float4*)(hrow + k0 + 4);
        bf16x8 af;
        af[0] = f2bf(v0.x); af[1] = f2bf(v0.y); af[2] = f2bf(v0.z); af[3] = f2bf(v0.w);
        af[4] = f2bf(v1.x); af[5] = f2bf(v1.y); af[6] = f2bf(v1.z); af[7] = f2bf(v1.w);
        #pragma unroll
        for (int c = 0; c < 4; ++c) {
            const short* bp = WT + (long)(colbase + c * 16 + lr) * FIN + k0 + lq * 8;
            bf16x8 bf = *(const bf16x8*)bp;
            acc[c] = __builtin_amdgcn_mfma_f32_16x16x32_bf16(af, bf, acc[c], 0, 0, 0);
        }
    }

    const int b   = (int)(row0 >> 10);
    const int il0 = (int)(row0 & 1023);
    // acc[c][jj] = Wh[row0 + lq*4 + jj][colbase + c*16 + lr]  (C/D map)
    // Bpack: kt = il0>>5; lane slot lp = (h16*2 + (lq>>1))*16 + lr, u0 = (lq&1)*4
    const int kt  = il0 >> 5;
    const int h16 = (il0 >> 4) & 1;
    const int lp  = (h16 * 2 + (lq >> 1)) * 16 + lr;
    const int u0  = (lq & 1) * 4;
    short* bpo = Bpack + ((long)b * 16 * 32) * 512;
    #pragma unroll
    for (int c = 0; c < 4; ++c) {
        short4 s;
        s.x = f2bf(acc[c][0]); s.y = f2bf(acc[c][1]);
        s.z = f2bf(acc[c][2]); s.w = f2bf(acc[c][3]);
        int n16 = w * 4 + c;
        *(short4*)(bpo + ((long)(n16 * 32 + kt)) * 512 + lp * 8 + u0) = s;
    }

    float p1[4] = {0.f, 0.f, 0.f, 0.f}, p2[4] = {0.f, 0.f, 0.f, 0.f};
    #pragma unroll
    for (int c = 0; c < 4; ++c) {
        int col = colbase + c * 16 + lr;
        float a1v = a[col], a2v = a[FOUT + col];
        #pragma unroll
        for (int j = 0; j < 4; ++j) { p1[j] += acc[c][j] * a1v; p2[j] += acc[c][j] * a2v; }
    }
    #pragma unroll
    for (int off = 1; off < 16; off <<= 1) {
        #pragma unroll
        for (int j = 0; j < 4; ++j) {
            p1[j] += __shfl_xor(p1[j], off, 64);
            p2[j] += __shfl_xor(p2[j], off, 64);
        }
    }
    if (lr == 0) {
        #pragma unroll
        for (int j = 0; j < 4; ++j) { r1[w][lq * 4 + j] = p1[j]; r2[w][lq * 4 + j] = p2[j]; }
    }
    __syncthreads();
    if (tid < 16) {
        F1[row0 + tid] = r1[0][tid] + r1[1][tid] + r1[2][tid] + r1[3][tid];
        F2[row0 + tid] = r2[0][tid] + r2[1][tid] + r2[2][tid] + r2[3][tid];
    }
}

// ---------------------------------------------------------------------------
// k_pv (fused): A-fragments (P = adj ? exp(leaky(f1+f2)) : 0, bf16, m=0
// shift-invariant softmax) generated IN REGISTERS in A-frag lane order,
// immediately consumed by MFMA against fragment-linear Bpack chunks.
// No P materialization (saves 32 MB traffic + a launch). l summed from the
// quantized fragments. Block = 512 thr / 8 waves = 2 rg x 2 cw x 2 kg:
// wave = 16 rows x 128 cols x K=512. Grid = (8, 32): blockIdx.x = batch
// pins each batch's Bpack slab (512 KB) to one XCD L2. Depth-1 adj
// prefetch; cross-kg LDS reduce; LN + exact GELU epilogue.
// ---------------------------------------------------------------------------
__global__ __launch_bounds__(512, 4) void k_pv(const short* __restrict__ Bpack,
                                               const float* __restrict__ adj,
                                               const float* __restrict__ F1,
                                               const float* __restrict__ F2,
                                               const float* __restrict__ gamma,
                                               const float* __restrict__ beta,
                                               float* __restrict__ out) {
    const int tid = threadIdx.x;
    const int b   = blockIdx.x;
    const int w   = tid >> 6, l = tid & 63;
    const int lr  = l & 15, lq = l >> 4;
    const int rg  = w >> 2;         // row group: rows m16*16..+15
    const int cw  = (w >> 1) & 1;   // col half: cols cw*128..+127
    const int kg  = w & 1;          // K half: kts kg*16..+15
    const int m16 = blockIdx.y * 2 + rg;
    const int i0  = m16 * 16;

    __shared__ float f2s[N_];                     // 4 KB
    __shared__ float sc[2][2][16][132];           // 67.6 KB cross-kg partials
    __shared__ float lnp1[2][2][16], lnp2[2][2][16];
    __shared__ float lsumS[2][2][16];             // [rg][kg][row]

    { int j = tid * 2; *(float2*)&f2s[j] = *(const float2*)(F2 + b * N_ + j); }
    __syncthreads();

    const float f1 = F1[b * N_ + i0 + lr];
    const float* __restrict__ arow = adj + ((long)b * N_ + i0 + lr) * N_;
    const short* __restrict__ bp = Bpack + (((long)b * 16 + cw * 8) * 32 + kg * 16) * 512 + l * 8;
    const int ktb = kg * 16;

    f32x4 acc[8] = {};
    float ls = 0.f;

    float aa[8];
    {
        int j0 = ktb * 32 + lq * 8;
        *(float4*)&aa[0] = *(const float4*)(arow + j0);
        *(float4*)&aa[4] = *(const float4*)(arow + j0 + 4);
    }

    #pragma unroll
    for (int t = 0; t < 16; ++t) {
        float aan[8];
        if (t < 15) {
            int j1 = (ktb + t + 1) * 32 + lq * 8;
            *(float4*)&aan[0] = *(const float4*)(arow + j1);
            *(float4*)&aan[4] = *(const float4*)(arow + j1 + 4);
        }
        const int j0 = (ktb + t) * 32 + lq * 8;
        float f2k[8];
        *(float4*)&f2k[0] = *(const float4*)&f2s[j0];
        *(float4*)&f2k[4] = *(const float4*)&f2s[j0 + 4];

        bf16x8 af;
        #pragma unroll
        for (int u = 0; u < 8; ++u) {
            float x = f1 + f2k[u];
            float tt = fmaxf(x, ALPHA * x);
            float e = (aa[u] > 0.f) ? __expf(tt) : 0.f;
            short s = f2bf_fast(e);
            af[u] = s;
            ls += bf2f(s);
        }

        #pragma unroll
        for (int cf = 0; cf < 8; ++cf) {
            bf16x8 bf = *(const bf16x8*)(bp + ((long)cf * 32 + t) * 512);
            acc[cf] = __builtin_amdgcn_mfma_f32_16x16x32_bf16(af, bf, acc[cf], 0, 0, 0);
        }
        if (t < 15) {
            #pragma unroll
            for (int u = 0; u < 8; ++u) aa[u] = aan[u];
        }
    }

    // row sums for this kg half (both cw waves compute identical ls; use cw=0)
    ls += __shfl_xor(ls, 16, 64);
    ls += __shfl_xor(ls, 32, 64);
    if (cw == 0 && lq == 0) lsumS[rg][kg][lr] = ls;

    // cross-kg reduce: kg=1 waves park partials in LDS
    if (kg == 1) {
        #pragma unroll
        for (int cf = 0; cf < 8; ++cf)
            #pragma unroll
            for (int jj = 0; jj < 4; ++jj)
                sc[rg][cw][lq * 4 + jj][cf * 16 + lr] = acc[cf][jj];
    }
    __syncthreads();

    if (kg == 0) {
        #pragma unroll
        for (int cf = 0; cf < 8; ++cf)
            #pragma unroll
            for (int jj = 0; jj < 4; ++jj)
                acc[cf][jj] += sc[rg][cw][lq * 4 + jj][cf * 16 + lr];

        // 1/l for local rows (combine kg halves)
        float il[4];
        #pragma unroll
        for (int jj = 0; jj < 4; ++jj) {
            float r = lsumS[rg][0][lq * 4 + jj] + lsumS[rg][1][lq * 4 + jj];
            il[jj] = (r > 0.f) ? 1.0f / r : 0.f;
        }
        float s1[4] = {0.f,0.f,0.f,0.f}, s2[4] = {0.f,0.f,0.f,0.f};
        #pragma unroll
        for (int cf = 0; cf < 8; ++cf)
            #pragma unroll
            for (int jj = 0; jj < 4; ++jj) {
                float v = acc[cf][jj] * il[jj];
                acc[cf][jj] = v;
                s1[jj] += v;
                s2[jj] += v * v;
            }
        #pragma unroll
        for (int off = 1; off < 16; off <<= 1)
            #pragma unroll
            for (int jj = 0; jj < 4; ++jj) {
                s1[jj] += __shfl_xor(s1[jj], off, 64);
                s2[jj] += __shfl_xor(s2[jj], off, 64);
            }
        if (lr == 0) {
            #pragma unroll
            for (int jj = 0; jj < 4; ++jj) {
                lnp1[rg][cw][lq * 4 + jj] = s1[jj];
                lnp2[rg][cw][lq * 4 + jj] = s2[jj];
            }
        }
    }
    __syncthreads();

    if (kg == 0) {
        #pragma unroll
        for (int jj = 0; jj < 4; ++jj) {
            int row = lq * 4 + jj;
            float t1 = lnp1[rg][0][row] + lnp1[rg][1][row];
            float t2 = lnp2[rg][0][row] + lnp2[rg][1][row];
            float mu   = t1 * (1.0f / FOUT);
            float rstd = rsqrtf(t2 * (1.0f / FOUT) - mu * mu + EPSV);
            #pragma unroll
            for (int cf = 0; cf < 8; ++cf) {
                int col = cw * 128 + cf * 16 + lr;
                out[((long)b * N_ + i0 + row) * FOUT + col] =
                    gelu_exact((acc[cf][jj] - mu) * rstd * gamma[col] + beta[col]);
            }
        }
    }
}

extern "C" void kernel_launch(void* const* d_in, const int* in_sizes, int n_in,
                              void* d_out, int out_size, void* d_ws, size_t ws_size,
                              hipStream_t stream) {
    const float* h     = (const float*)d_in[0];
    const float* adj   = (const float*)d_in[1];
    // d_in[2]=q_type, d_in[3]=pos : unused scalars
    const float* W     = (const float*)d_in[4];
    const float* a     = (const float*)d_in[5];
    const float* gamma = (const float*)d_in[6];
    const float* beta  = (const float*)d_in[7];
    float* out = (float*)d_out;

    // workspace layout (~4.5 MB)
    short* Bpack = (short*)d_ws;                         // 8*16*32*512 = 4 MB
    short* WT    = Bpack + (size_t)B_ * 16 * 32 * 512;   // 256 KB
    float* F1    = (float*)(WT + (size_t)FOUT * FIN);    // 32 KB
    float* F2    = F1 + (size_t)B_ * N_;

    k_prep<<<dim3(128), 256, 0, stream>>>(W, WT);
    k_wh  <<<dim3(B_ * N_ / 16), 256, 0, stream>>>(h, WT, a, Bpack, F1, F2);
    k_pv  <<<dim3(B_, N_ / 32), 512, 0, stream>>>(Bpack, adj, F1, F2, gamma, beta, out);
}

// Round 10
// 60.334 us; speedup vs baseline: 1.3192x; 1.3192x over previous
//
#include <hip/hip_runtime.h>
#include <math.h>

#define B_    8
#define N_    1024
#define FIN   512
#define FOUT  256
#define ALPHA 0.2f
#define EPSV  1e-5f

typedef __attribute__((ext_vector_type(8))) short bf16x8;
typedef __attribute__((ext_vector_type(4))) float f32x4;

__device__ __forceinline__ short f2bf(float x) {          // RNE
    unsigned u = __builtin_bit_cast(unsigned, x);
    u = (u + 0x7FFFu + ((u >> 16) & 1u)) >> 16;
    return (short)u;
}
__device__ __forceinline__ short f2bf_fast(float x) {     // round-half-up (P path)
    unsigned u = __builtin_bit_cast(unsigned, x);
    return (short)((u + 0x8000u) >> 16);
}
__device__ __forceinline__ float bf2f(short s) {
    return __builtin_bit_cast(float, ((unsigned)(unsigned short)s) << 16);
}
__device__ __forceinline__ float gelu_exact(float x) {
    return 0.5f * x * (1.0f + erff(x * 0.70710678118654752f));
}

// Bpack fragment-linear chunks (1 KB = 64 lanes x 16B):
//   Bpack[b][n16][kt][l][u8] : lane l=(lq*16+lr) holds Wh[kt*32+lq*8+u][n16*16+lr]
// Bit matrix (A-frag byte order): byte at bits[row*128 + lq*32 + kt] holds
//   adj bits for j = kt*32 + lq*8 + u  (u = bit index 0..7).

// ---------------------------------------------------------------------------
// k_prep: W (512x256 fp32 row-major) -> WT (256x512 bf16, [col][k]).
// ---------------------------------------------------------------------------
__global__ __launch_bounds__(256) void k_prep(const float* __restrict__ W,
                                              short* __restrict__ WT) {
    int id  = blockIdx.x * 256 + threadIdx.x;
    int col = id >> 7;
    int k4  = (id & 127) * 4;
    short4 v;
    v.x = f2bf(W[(k4 + 0) * FOUT + col]);
    v.y = f2bf(W[(k4 + 1) * FOUT + col]);
    v.z = f2bf(W[(k4 + 2) * FOUT + col]);
    v.w = f2bf(W[(k4 + 3) * FOUT + col]);
    *(short4*)(WT + (long)col * FIN + k4) = v;
}

// ---------------------------------------------------------------------------
// k_bits: adj (fp32, read once, fully coalesced 2KB/wave) -> 1-bit mask
// matrix in A-frag byte order. One wave per row; per-lane byte build, then
// ds_bpermute to dest order; 128B contiguous store per row. Grid = 2048.
// ---------------------------------------------------------------------------
__global__ __launch_bounds__(256) void k_bits(const float* __restrict__ adj,
                                              unsigned char* __restrict__ bits) {
    const int tid = threadIdx.x;
    const int w   = tid >> 6, l = tid & 63;
    const long gr = (long)blockIdx.x * 4 + w;          // global row 0..8191
    const float* __restrict__ arow = adj + gr * N_;

    unsigned b0 = 0, b1 = 0;
    {
        float4 x0 = *(const float4*)(arow + l * 8);
        float4 x1 = *(const float4*)(arow + l * 8 + 4);
        float aa[8] = {x0.x, x0.y, x0.z, x0.w, x1.x, x1.y, x1.z, x1.w};
        #pragma unroll
        for (int u = 0; u < 8; ++u) b0 |= (aa[u] > 0.f ? 1u : 0u) << u;
        float4 y0 = *(const float4*)(arow + 512 + l * 8);
        float4 y1 = *(const float4*)(arow + 512 + l * 8 + 4);
        float bb[8] = {y0.x, y0.y, y0.z, y0.w, y1.x, y1.y, y1.z, y1.w};
        #pragma unroll
        for (int u = 0; u < 8; ++u) b1 |= (bb[u] > 0.f ? 1u : 0u) << u;
    }
    // lane l built: b0 = bits of j=l*8..+7 (pass0), b1 = j=512+l*8..+7 (pass1)
    // dest byte o (0..127): lq = o>>5, kt = o&31; src lane = ((kt&15)<<2)|lq,
    // pass = kt>>4. Lane l writes bytes o = 2l, 2l+1 (contiguous u16).
    unsigned out2 = 0;
    #pragma unroll
    for (int k = 0; k < 2; ++k) {
        int o   = 2 * l + k;
        int lqd = o >> 5, ktd = o & 31;
        int src = ((ktd & 15) << 2) | lqd;
        unsigned v0 = __shfl(b0, src, 64);
        unsigned v1 = __shfl(b1, src, 64);
        unsigned v  = (ktd & 16) ? v1 : v0;
        out2 |= (v & 0xFFu) << (8 * k);
    }
    *(unsigned short*)(bits + gr * 128 + l * 2) = (unsigned short)out2;
}

// ---------------------------------------------------------------------------
// k_wh: Wh = h @ W via bf16 MFMA; writes Bpack (fragment-linear) + F1/F2.
// Block = 256 thr / 4 waves; 16 node-rows; grid = 512.
// ---------------------------------------------------------------------------
__global__ __launch_bounds__(256) void k_wh(const float* __restrict__ h,
                                            const short* __restrict__ WT,
                                            const float* __restrict__ a,
                                            short* __restrict__ Bpack,
                                            float* __restrict__ F1,
                                            float* __restrict__ F2) {
    const int tid = threadIdx.x;
    const int w   = tid >> 6, l = tid & 63;
    const int lr  = l & 15, lq = l >> 4;
    const long row0 = (long)blockIdx.x * 16;
    const int colbase = w * 64;

    __shared__ float r1[4][16], r2[4][16];

    f32x4 acc[4] = {};
    const float* hrow = h + (row0 + lr) * FIN + lq * 8;

    #pragma unroll
    for (int k0 = 0; k0 < FIN; k0 += 32) {
        float4 v0 = *(const float4*)(hrow + k0);
        float4 v1 = *(const float4*)(hrow + k0 + 4);
        bf16x8 af;
        af[0] = f2bf(v0.x); af[1] = f2bf(v0.y); af[2] = f2bf(v0.z); af[3] = f2bf(v0.w);
        af[4] = f2bf(v1.x); af[5] = f2bf(v1.y); af[6] = f2bf(v1.z); af[7] = f2bf(v1.w);
        #pragma unroll
        for (int c = 0; c < 4; ++c) {
            const short* bp = WT + (long)(colbase + c * 16 + lr) * FIN + k0 + lq * 8;
            bf16x8 bf = *(const bf16x8*)bp;
            acc[c] = __builtin_amdgcn_mfma_f32_16x16x32_bf16(af, bf, acc[c], 0, 0, 0);
        }
    }

    const int b   = (int)(row0 >> 10);
    const int il0 = (int)(row0 & 1023);
    const int kt  = il0 >> 5;
    const int h16 = (il0 >> 4) & 1;
    const int lp  = (h16 * 2 + (lq >> 1)) * 16 + lr;
    const int u0  = (lq & 1) * 4;
    short* bpo = Bpack + ((long)b * 16 * 32) * 512;
    #pragma unroll
    for (int c = 0; c < 4; ++c) {
        short4 s;
        s.x = f2bf(acc[c][0]); s.y = f2bf(acc[c][1]);
        s.z = f2bf(acc[c][2]); s.w = f2bf(acc[c][3]);
        int n16 = w * 4 + c;
        *(short4*)(bpo + ((long)(n16 * 32 + kt)) * 512 + lp * 8 + u0) = s;
    }

    float p1[4] = {0.f, 0.f, 0.f, 0.f}, p2[4] = {0.f, 0.f, 0.f, 0.f};
    #pragma unroll
    for (int c = 0; c < 4; ++c) {
        int col = colbase + c * 16 + lr;
        float a1v = a[col], a2v = a[FOUT + col];
        #pragma unroll
        for (int j = 0; j < 4; ++j) { p1[j] += acc[c][j] * a1v; p2[j] += acc[c][j] * a2v; }
    }
    #pragma unroll
    for (int off = 1; off < 16; off <<= 1) {
        #pragma unroll
        for (int j = 0; j < 4; ++j) {
            p1[j] += __shfl_xor(p1[j], off, 64);
            p2[j] += __shfl_xor(p2[j], off, 64);
        }
    }
    if (lr == 0) {
        #pragma unroll
        for (int j = 0; j < 4; ++j) { r1[w][lq * 4 + j] = p1[j]; r2[w][lq * 4 + j] = p2[j]; }
    }
    __syncthreads();
    if (tid < 16) {
        F1[row0 + tid] = r1[0][tid] + r1[1][tid] + r1[2][tid] + r1[3][tid];
        F2[row0 + tid] = r2[0][tid] + r2[1][tid] + r2[2][tid] + r2[3][tid];
    }
}

// ---------------------------------------------------------------------------
// k_pv v3 (fused): P = bit ? exp(leaky(f1+f2)) : 0 generated in registers in
// A-frag order; mask comes from ONE 32B bit-load per lane (statically indexed
// per t). Main-loop memory ops: LDS f2 reads + L2-resident Bpack frags only.
// Block = 256 thr / 4 col-waves; tile = 16 rows x 256 cols; K = 1024/wave.
// Grid = (8, 64): blockIdx.x = batch pins Bpack slab to one XCD L2.
// l summed from quantized fragments; LN + exact GELU epilogue.
// ---------------------------------------------------------------------------
__global__ __launch_bounds__(256) void k_pv(const short* __restrict__ Bpack,
                                            const unsigned char* __restrict__ bits,
                                            const float* __restrict__ F1,
                                            const float* __restrict__ F2,
                                            const float* __restrict__ gamma,
                                            const float* __restrict__ beta,
                                            float* __restrict__ out) {
    const int tid = threadIdx.x;
    const int b   = blockIdx.x;
    const int i0  = blockIdx.y * 16;
    const int w   = tid >> 6, l = tid & 63;    // w = col wave (64 cols)
    const int lr  = l & 15, lq = l >> 4;

    __shared__ float f2s[N_];                  // 4 KB
    __shared__ float lnp1[4][16], lnp2[4][16];

    { int j = tid * 4; *(float4*)&f2s[j] = *(const float4*)(F2 + b * N_ + j); }
    __syncthreads();

    const float f1 = F1[b * N_ + i0 + lr];
    // 32 mask bytes for (row=i0+lr, lq): kt = 0..31
    unsigned bw[8];
    {
        const unsigned char* pb = bits + ((long)(b * N_ + i0 + lr)) * 128 + lq * 32;
        uint4 q0 = *(const uint4*)pb;
        uint4 q1 = *(const uint4*)(pb + 16);
        bw[0]=q0.x; bw[1]=q0.y; bw[2]=q0.z; bw[3]=q0.w;
        bw[4]=q1.x; bw[5]=q1.y; bw[6]=q1.z; bw[7]=q1.w;
    }
    const short* __restrict__ bp = Bpack + (((long)b * 16 + w * 4) * 32) * 512 + l * 8;

    f32x4 acc[4] = {};
    float ls = 0.f;

    bf16x8 bc0 = *(const bf16x8*)(bp);
    bf16x8 bc1 = *(const bf16x8*)(bp + 32 * 512);
    bf16x8 bc2 = *(const bf16x8*)(bp + 64 * 512);
    bf16x8 bc3 = *(const bf16x8*)(bp + 96 * 512);

    #pragma unroll
    for (int t = 0; t < 32; ++t) {
        bf16x8 bn0 = bc0, bn1 = bc1, bn2 = bc2, bn3 = bc3;
        if (t < 31) {
            bn0 = *(const bf16x8*)(bp + (t + 1) * 512);
            bn1 = *(const bf16x8*)(bp + (32 + t + 1) * 512);
            bn2 = *(const bf16x8*)(bp + (64 + t + 1) * 512);
            bn3 = *(const bf16x8*)(bp + (96 + t + 1) * 512);
        }
        float f2k[8];
        *(float4*)&f2k[0] = *(const float4*)&f2s[t * 32 + lq * 8];
        *(float4*)&f2k[4] = *(const float4*)&f2s[t * 32 + lq * 8 + 4];
        const unsigned byte = (bw[t >> 2] >> ((t & 3) * 8)) & 0xFFu;

        bf16x8 af;
        #pragma unroll
        for (int u = 0; u < 8; ++u) {
            float x  = f1 + f2k[u];
            float tt = fmaxf(x, ALPHA * x);
            float e  = ((byte >> u) & 1u) ? __expf(tt) : 0.f;
            short s  = f2bf_fast(e);
            af[u] = s;
            ls += bf2f(s);
        }
        acc[0] = __builtin_amdgcn_mfma_f32_16x16x32_bf16(af, bc0, acc[0], 0, 0, 0);
        acc[1] = __builtin_amdgcn_mfma_f32_16x16x32_bf16(af, bc1, acc[1], 0, 0, 0);
        acc[2] = __builtin_amdgcn_mfma_f32_16x16x32_bf16(af, bc2, acc[2], 0, 0, 0);
        acc[3] = __builtin_amdgcn_mfma_f32_16x16x32_bf16(af, bc3, acc[3], 0, 0, 0);
        bc0 = bn0; bc1 = bn1; bc2 = bn2; bc3 = bn3;
    }

    // row sums: reduce over lq -> every lane holds its lr's full row sum
    ls += __shfl_xor(ls, 16, 64);
    ls += __shfl_xor(ls, 32, 64);
    float il[4];
    #pragma unroll
    for (int jj = 0; jj < 4; ++jj) {
        float r = __shfl(ls, lq * 4 + jj, 64);
        il[jj] = (r > 0.f) ? 1.0f / r : 0.f;
    }

    // LN partials over this wave's 64 cols
    float s1[4] = {0.f,0.f,0.f,0.f}, s2[4] = {0.f,0.f,0.f,0.f};
    #pragma unroll
    for (int cf = 0; cf < 4; ++cf)
        #pragma unroll
        for (int jj = 0; jj < 4; ++jj) {
            float v = acc[cf][jj] * il[jj];
            acc[cf][jj] = v;
            s1[jj] += v;
            s2[jj] += v * v;
        }
    #pragma unroll
    for (int off = 1; off < 16; off <<= 1)
        #pragma unroll
        for (int jj = 0; jj < 4; ++jj) {
            s1[jj] += __shfl_xor(s1[jj], off, 64);
            s2[jj] += __shfl_xor(s2[jj], off, 64);
        }
    if (lr == 0) {
        #pragma unroll
        for (int jj = 0; jj < 4; ++jj) {
            lnp1[w][lq * 4 + jj] = s1[jj];
            lnp2[w][lq * 4 + jj] = s2[jj];
        }
    }
    __syncthreads();

    #pragma unroll
    for (int jj = 0; jj < 4; ++jj) {
        int row = lq * 4 + jj;
        float t1 = lnp1[0][row] + lnp1[1][row] + lnp1[2][row] + lnp1[3][row];
        float t2 = lnp2[0][row] + lnp2[1][row] + lnp2[2][row] + lnp2[3][row];
        float mu   = t1 * (1.0f / FOUT);
        float rstd = rsqrtf(t2 * (1.0f / FOUT) - mu * mu + EPSV);
        #pragma unroll
        for (int cf = 0; cf < 4; ++cf) {
            int col = w * 64 + cf * 16 + lr;
            out[((long)b * N_ + i0 + row) * FOUT + col] =
                gelu_exact((acc[cf][jj] - mu) * rstd * gamma[col] + beta[col]);
        }
    }
}

extern "C" void kernel_launch(void* const* d_in, const int* in_sizes, int n_in,
                              void* d_out, int out_size, void* d_ws, size_t ws_size,
                              hipStream_t stream) {
    const float* h     = (const float*)d_in[0];
    const float* adj   = (const float*)d_in[1];
    // d_in[2]=q_type, d_in[3]=pos : unused scalars
    const float* W     = (const float*)d_in[4];
    const float* a     = (const float*)d_in[5];
    const float* gamma = (const float*)d_in[6];
    const float* beta  = (const float*)d_in[7];
    float* out = (float*)d_out;

    // workspace layout (~5.6 MB)
    short* Bpack = (short*)d_ws;                          // 8*16*32*512 = 4 MB
    short* WT    = Bpack + (size_t)B_ * 16 * 32 * 512;    // 256 KB
    float* F1    = (float*)(WT + (size_t)FOUT * FIN);     // 32 KB
    float* F2    = F1 + (size_t)B_ * N_;                  // 32 KB
    unsigned char* bits = (unsigned char*)(F2 + (size_t)B_ * N_);  // 1 MB

    k_prep<<<dim3(128), 256, 0, stream>>>(W, WT);
    k_bits<<<dim3(B_ * N_ / 4), 256, 0, stream>>>(adj, bits);
    k_wh  <<<dim3(B_ * N_ / 16), 256, 0, stream>>>(h, WT, a, Bpack, F1, F2);
    k_pv  <<<dim3(B_, N_ / 16), 256, 0, stream>>>(Bpack, bits, F1, F2, gamma, beta, out);
}